// Round 1
// baseline (171.034 us; speedup 1.0000x reference)
//
#include <hip/hip_runtime.h>

// Problem constants (fixed by reference: B=64, T=1024, D=256)
constexpr int Bn = 64;
constexpr int Tn = 1024;
constexpr int Dn = 256;

constexpr int TPB    = 256;         // 4 waves
constexpr int NBLK   = 512;         // 2 blocks/CU on 256 CUs
constexpr int TPERB  = Tn / NBLK;   // 2 t-slices per block
constexpr int KC     = 64;          // d-chunk staged in LDS
constexpr int NCHUNK = Dn / KC;     // 4
constexpr int PITCH  = KC + 4;      // 68 floats: 272B rows -> 16B aligned, conflict-free

__device__ __forceinline__ float dot4(const float4& a, const float4& b) {
    return a.x * b.x + a.y * b.y + a.z * b.z + a.w * b.w;
}

__global__ __launch_bounds__(TPB, 2)
void cmfm_main(const float* __restrict__ fv, const float* __restrict__ fa,
               const int* __restrict__ labels, float* __restrict__ acc) {
    __shared__ __align__(16) float Vs[Bn][PITCH];   // [i][d]  raw v chunk
    __shared__ __align__(16) float As[KC][PITCH];   // [d][j]  raw a chunk (transposed)
    __shared__ float rvs[Bn];
    __shared__ float ras[Bn];
    __shared__ float wred[3][TPB / 64];

    const int tid = threadIdx.x;
    const int row = tid >> 2;      // loader row 0..63 (same row for V and A)
    const int q   = tid & 3;       // quarter of the row
    const int tx  = tid & 15;      // C-tile col group
    const int ty  = tid >> 4;      // C-tile row group
    const int i0  = ty * 4;
    const int j0  = tx * 4;

    const int lab = labels[row];

    const float4* __restrict__ fv4 = reinterpret_cast<const float4*>(fv);
    const float4* __restrict__ fa4 = reinterpret_cast<const float4*>(fa);

    float C[4][4] = {};
    float pos_acc = 0.f, neg_acc = 0.f;

    for (int tt = 0; tt < TPERB; ++tt) {
        const int t = blockIdx.x * TPERB + tt;
        // base index (in float4 units) of row `row` at timestep t
        const size_t base = ((size_t)row * Tn + t) * (Dn / 4);

        float S[4][4] = {};
        float sqv = 0.f, sqa = 0.f, dva = 0.f;

        for (int c = 0; c < NCHUNK; ++c) {
            // ---------- stage chunk c (raw) + norm accumulation ----------
            const size_t f4base = base + (size_t)c * (KC / 4);
            float4 v4[4], a4[4];
            #pragma unroll
            for (int k = 0; k < 4; ++k) {
                const int f4i = q + 4 * k;          // 0..15 within chunk
                v4[k] = fv4[f4base + f4i];
                a4[k] = fa4[f4base + f4i];
            }
            #pragma unroll
            for (int k = 0; k < 4; ++k) {
                sqv += dot4(v4[k], v4[k]);
                sqa += dot4(a4[k], a4[k]);
                dva += dot4(v4[k], a4[k]);
                const int d = (q + 4 * k) * 4;      // within-chunk d (0..60)
                *reinterpret_cast<float4*>(&Vs[row][d]) = v4[k];
                As[d + 0][row] = a4[k].x;
                As[d + 1][row] = a4[k].y;
                As[d + 2][row] = a4[k].z;
                As[d + 3][row] = a4[k].w;
            }
            __syncthreads();

            // ---------- GEMM on chunk (unscaled) ----------
            #pragma unroll
            for (int d4 = 0; d4 < KC / 4; ++d4) {
                float va[4][4], ab[4][4];
                #pragma unroll
                for (int r = 0; r < 4; ++r) {
                    float4 v = *reinterpret_cast<const float4*>(&Vs[i0 + r][d4 * 4]);
                    va[r][0] = v.x; va[r][1] = v.y; va[r][2] = v.z; va[r][3] = v.w;
                }
                #pragma unroll
                for (int m = 0; m < 4; ++m) {
                    float4 a = *reinterpret_cast<const float4*>(&As[d4 * 4 + m][j0]);
                    ab[m][0] = a.x; ab[m][1] = a.y; ab[m][2] = a.z; ab[m][3] = a.w;
                }
                #pragma unroll
                for (int dd = 0; dd < 4; ++dd)
                    #pragma unroll
                    for (int r = 0; r < 4; ++r)
                        #pragma unroll
                        for (int s = 0; s < 4; ++s)
                            S[r][s] = fmaf(va[r][dd], ab[dd][s], S[r][s]);
            }
            __syncthreads();
        }

        // ---------- per-row norms: reduce across the 4 quarter-threads ----------
        sqv += __shfl_xor(sqv, 1); sqv += __shfl_xor(sqv, 2);
        sqa += __shfl_xor(sqa, 1); sqa += __shfl_xor(sqa, 2);
        dva += __shfl_xor(dva, 1); dva += __shfl_xor(dva, 2);
        const float rv = 1.f / fmaxf(sqrtf(sqv), 1e-8f);
        const float ra = 1.f / fmaxf(sqrtf(sqa), 1e-8f);
        if (q == 0) {
            rvs[row] = rv;
            ras[row] = ra;
            const float cosd = dva * rv * ra;       // aligned-pair cosine
            if (lab == 0) pos_acc += 1.f - cosd;    // d_bt = 1 - cos
            else          neg_acc += cosd;          // (1 - d_bt) = cos
        }
        __syncthreads();

        // ---------- fold scaling into accumulator: C += rv_i * ra_j * S ----------
        float rvv[4], raa[4];
        #pragma unroll
        for (int r = 0; r < 4; ++r) rvv[r] = rvs[i0 + r];
        #pragma unroll
        for (int s = 0; s < 4; ++s) raa[s] = ras[j0 + s];
        #pragma unroll
        for (int r = 0; r < 4; ++r)
            #pragma unroll
            for (int s = 0; s < 4; ++s)
                C[r][s] = fmaf(rvv[r] * raa[s], S[r][s], C[r][s]);
        __syncthreads();   // protect rvs/ras before next t overwrites
    }

    // ---------- epilogue: off-diagonal sum + block reduce + 3 atomics ----------
    float od = 0.f;
    #pragma unroll
    for (int r = 0; r < 4; ++r)
        #pragma unroll
        for (int s = 0; s < 4; ++s) od += C[r][s];
    if (ty == tx) {
        #pragma unroll
        for (int r = 0; r < 4; ++r) od -= C[r][r];  // remove i==j diagonal
    }

    #pragma unroll
    for (int off = 1; off < 64; off <<= 1) {
        pos_acc += __shfl_xor(pos_acc, off);
        neg_acc += __shfl_xor(neg_acc, off);
        od      += __shfl_xor(od, off);
    }
    const int wave = tid >> 6;
    const int lane = tid & 63;
    if (lane == 0) {
        wred[0][wave] = pos_acc;
        wred[1][wave] = neg_acc;
        wred[2][wave] = od;
    }
    __syncthreads();
    if (tid == 0) {
        float p = 0.f, n = 0.f, o = 0.f;
        #pragma unroll
        for (int w = 0; w < TPB / 64; ++w) { p += wred[0][w]; n += wred[1][w]; o += wred[2][w]; }
        atomicAdd(&acc[0], p);
        atomicAdd(&acc[1], n);
        atomicAdd(&acc[2], o);
    }
}

__global__ void cmfm_final(const int* __restrict__ labels, const float* __restrict__ acc,
                           float* __restrict__ out) {
    if (threadIdx.x == 0) {
        int npos = 0;
        for (int i = 0; i < Bn; ++i) npos += (labels[i] == 0);
        const float pos_sum   = acc[0];
        const float neg_sum   = acc[1];
        const float cross_sum = acc[2];   // Sigma_{i!=j} Sigma_{t,d} vn*an  (== T * cross_cos sum)

        const float cnt_pos = (float)npos * (float)Tn;
        const float cnt_neg = (float)(Bn - npos) * (float)Tn + (float)Bn * (float)(Bn - 1);

        float loss = 0.f;
        if (npos > 0) loss += 2.0f * pos_sum / cnt_pos;                       // ALPHA
        loss += (2.0f * neg_sum + 1.0f * cross_sum / (float)Tn) / cnt_neg;    // BETA, GAMMA
        out[0] = loss;
    }
}

extern "C" void kernel_launch(void* const* d_in, const int* in_sizes, int n_in,
                              void* d_out, int out_size, void* d_ws, size_t ws_size,
                              hipStream_t stream) {
    const float* fv     = (const float*)d_in[0];
    const float* fa     = (const float*)d_in[1];
    const int*   labels = (const int*)d_in[2];
    float* acc = (float*)d_ws;        // [0]=pos_sum [1]=neg_sum [2]=cross_sum
    float* out = (float*)d_out;

    hipMemsetAsync(acc, 0, 3 * sizeof(float), stream);
    cmfm_main<<<NBLK, TPB, 0, stream>>>(fv, fa, labels, acc);
    cmfm_final<<<1, 64, 0, stream>>>(labels, acc, out);
}